// Round 15
// baseline (27.880 us; speedup 1.0000x reference)
//
#include <hip/hip_runtime.h>

static constexpr float INV_SQRT2 = 0.70710678118654752f;
static constexpr float INV_SQRT3 = 0.57735026918962576f;
static constexpr float SQRT2     = 1.41421356237309505f;
static constexpr float INV_SQRT6 = 0.40824829046386302f;

static constexpr int W_GRAPHS = 8;   // graphs per wave
static constexpr int B_GRAPHS = 32;  // graphs per block (4 waves)
static constexpr int NSLOT    = 4;   // LDS slots/wave; 2 stages in flight

// branchless fast tanh: 1 - 2/(exp(2x)+1); exact at +/-inf, err ~1e-7
__device__ __forceinline__ float fast_tanh(float x) {
    const float e = __builtin_amdgcn_exp2f(x * 2.8853900817779268f); // 2*log2(e)
    const float r = __builtin_amdgcn_rcpf(e + 1.0f);
    return fmaf(-2.0f, r, 1.0f);
}

__device__ __forceinline__ float gate_p(float k, float fw) { return k > 0.f ? k * fw : 0.f; }
__device__ __forceinline__ float gate_n(float k, float fw) { return k < 0.f ? k * fw : 0.f; }

typedef const __attribute__((address_space(1))) void gvoid_t;
typedef __attribute__((address_space(3))) void lvoid_t;

// Block owns 32 graphs; wave 0 finds the 33 boundaries once (r13). Each wave
// walks its 8 graphs' union range with a global_load_lds software pipeline.
// r14 lesson: size=12 DMA produced garbage LDS (unverified lane stride) ->
// NaN. Now ONLY size=4 DMAs (HW-verified layout: dest = base + lane*4):
// stage = z (1 load) + pos channels c=0,1,2 (3 loads, per-lane source
// pos+3*gi+c, transposed LDS [c][64]). Counted s_waitcnt vmcnt(4) in steady
// state (never 0 until last), sched_barrier(0) after each wait (rule #18).
__global__ __launch_bounds__(256) void e3nn_fused(
    const int*   __restrict__ z,
    const float* __restrict__ pos,
    const int*   __restrict__ batch,
    const float* __restrict__ w_tp,
    const float* __restrict__ fc_w,
    const float* __restrict__ fc_b,
    float*       __restrict__ out,
    int n, int n_graphs)
{
    const int tid  = threadIdx.x;
    const int wid  = tid >> 6;
    const int lane = tid & 63;
    const int bg0  = blockIdx.x * B_GRAPHS;
    if (bg0 >= n_graphs) return;

    __shared__ int   sbnd[B_GRAPHS + 1];
    __shared__ int   zb[4][NSLOT][64];          // 4 KB
    __shared__ float pb[4][NSLOT][3][64];       // 12 KB, transposed channels

    // ---- wave 0: cooperative boundary search ----
    if (wid == 0) {
        const int tl     = (lane < B_GRAPHS) ? lane : B_GRAPHS;
        const int target = bg0 + tl;
        unsigned p2 = 1;
        while (p2 < (unsigned)n) p2 <<= 1;
        int bv = 0;
        for (unsigned step = p2 >> 1; step > 0; step >>= 1) {
            const unsigned cand = (unsigned)bv + step;
            if (cand <= (unsigned)n && batch[cand - 1] < target) bv = (int)cand;
        }
        if (lane <= B_GRAPHS) sbnd[lane] = bv;
    }
    __syncthreads();

    // ---- uniform weight prep ----
    const float kA0 = w_tp[0] * INV_SQRT2;
    const float kA1 = w_tp[1] * INV_SQRT2;
    const float kB0 = w_tp[2] * (INV_SQRT3 * INV_SQRT2);
    const float kB1 = w_tp[3] * (INV_SQRT3 * INV_SQRT2);
    const float c0  = (w_tp[4] + w_tp[6]) * INV_SQRT2;
    const float c1  = (w_tp[5] + w_tp[7]) * INV_SQRT2;
    const float wE  = w_tp[8];
    const float fw0 = fc_w[0], fw1 = fc_w[1];
    const float fb  = fc_b[0];

    const float P0 = gate_p(c0, fc_w[2]) + gate_p(c1, fc_w[5]);
    const float N0 = gate_n(c0, fc_w[2]) + gate_n(c1, fc_w[5]);
    const float P1 = gate_p(c0, fc_w[3]) + gate_p(c1, fc_w[6]);
    const float N1 = gate_n(c0, fc_w[3]) + gate_n(c1, fc_w[6]);
    const float P2 = gate_p(c0, fc_w[4]) + gate_p(c1, fc_w[7]);
    const float N2 = gate_n(c0, fc_w[4]) + gate_n(c1, fc_w[7]);
    const float k8  = wE * SQRT2,     k11 = wE * INV_SQRT2, k12 = wE * INV_SQRT6;
    const float P8  = gate_p(k8,  fc_w[8]),  N8  = gate_n(k8,  fc_w[8]);
    const float P9  = gate_p(k8,  fc_w[9]),  N9  = gate_n(k8,  fc_w[9]);
    const float P10 = gate_p(k8,  fc_w[10]), N10 = gate_n(k8,  fc_w[10]);
    const float P11 = gate_p(k11, fc_w[11]), N11 = gate_n(k11, fc_w[11]);
    const float P12 = gate_p(k12, fc_w[12]), N12 = gate_n(k12, fc_w[12]);

    // ---- this wave's boundaries ----
    const int wb = wid * W_GRAPHS;
    const int B0 = sbnd[wb + 0], B1 = sbnd[wb + 1];
    const int B2 = sbnd[wb + 2], B3 = sbnd[wb + 3];
    const int B4 = sbnd[wb + 4], B5 = sbnd[wb + 5];
    const int B6 = sbnd[wb + 6], B7 = sbnd[wb + 7];
    const int B8 = sbnd[wb + 8];
    const int myb = sbnd[wb + ((lane < W_GRAPHS) ? lane : W_GRAPHS)];
    const int nbv = sbnd[wb + ((lane < W_GRAPHS) ? lane + 1 : W_GRAPHS)];

    const int T = (B8 - B0) >> 6;   // full 64-node iterations

    // stage chunk s into slot s%NSLOT: 4 verified size-4 DMAs.
    auto stage = [&](int s) {
        const int sl = s & (NSLOT - 1);
        const int gi = B0 + (s << 6) + lane;
        __builtin_amdgcn_global_load_lds((gvoid_t*)(z + gi),
                                         (lvoid_t*)&zb[wid][sl][0], 4, 0, 0);
        __builtin_amdgcn_global_load_lds((gvoid_t*)(pos + 3 * gi + 0),
                                         (lvoid_t*)&pb[wid][sl][0][0], 4, 0, 0);
        __builtin_amdgcn_global_load_lds((gvoid_t*)(pos + 3 * gi + 1),
                                         (lvoid_t*)&pb[wid][sl][1][0], 4, 0, 0);
        __builtin_amdgcn_global_load_lds((gvoid_t*)(pos + 3 * gi + 2),
                                         (lvoid_t*)&pb[wid][sl][2][0], 4, 0, 0);
    };

    if (T > 0) stage(0);
    if (T > 1) stage(1);

    float tot = 0.f, s1 = 0.f, s2 = 0.f, s3 = 0.f;
    float s4  = 0.f, s5 = 0.f, s6 = 0.f, s7 = 0.f;

    auto body = [&](int i, float sc, float v0, float v1, float v2, bool valid) {
        const float v00 = v0 * v0, v11 = v1 * v1, v22 = v2 * v2;
        const float ss  = sc * sc;
        const float dr  = v00 + v11 + v22;

        float acc = fb;
        const float x0 = fmaf(ss, kA0, dr * kB0);
        const float x1 = fmaf(ss, kA1, dr * kB1);
        acc = fmaf(fmaxf(x0, 0.f), fw0, acc);
        acc = fmaf(fmaxf(x1, 0.f), fw1, acc);

        const float sv0 = sc * v0, sv1 = sc * v1, sv2 = sc * v2;
        acc = fmaf(sv0, (sv0 > 0.f ? P0 : N0), acc);
        acc = fmaf(sv1, (sv1 > 0.f ? P1 : N1), acc);
        acc = fmaf(sv2, (sv2 > 0.f ? P2 : N2), acc);

        const float t8 = v0 * v1, t9 = v1 * v2, t10 = v0 * v2;
        acc = fmaf(t8,  (t8  > 0.f ? P8  : N8 ), acc);
        acc = fmaf(t9,  (t9  > 0.f ? P9  : N9 ), acc);
        acc = fmaf(t10, (t10 > 0.f ? P10 : N10), acc);

        const float t11 = v00 - v11;
        acc = fmaf(t11, (t11 > 0.f ? P11 : N11), acc);
        const float t12 = (v22 - v00) + (v22 - v11);
        acc = fmaf(t12, (t12 > 0.f ? P12 : N12), acc);

        float y = fast_tanh(acc);
        if (!valid) y = 0.f;   // folds away for full iterations

        tot += y;
        s1 += (i >= B1) ? y : 0.f;
        s2 += (i >= B2) ? y : 0.f;
        s3 += (i >= B3) ? y : 0.f;
        s4 += (i >= B4) ? y : 0.f;
        s5 += (i >= B5) ? y : 0.f;
        s6 += (i >= B6) ? y : 0.f;
        s7 += (i >= B7) ? y : 0.f;
    };

#pragma unroll 1
    for (int t = 0; t < T; ++t) {
        // counted wait: stage t (oldest 4 loads) complete; t+1 stays in flight
        if (t + 1 < T) { asm volatile("s_waitcnt vmcnt(4)" ::: "memory"); }
        else           { asm volatile("s_waitcnt vmcnt(0)" ::: "memory"); }
        __builtin_amdgcn_sched_barrier(0);
        const int sl = t & (NSLOT - 1);
        const float sc = (float)zb[wid][sl][lane];
        const float v0 = pb[wid][sl][0][lane];
        const float v1 = pb[wid][sl][1][lane];
        const float v2 = pb[wid][sl][2][lane];
        if (t + 2 < T) stage(t + 2);   // slot (t+2)%4 != t%4: no race
        body(B0 + (t << 6) + lane, sc, v0, v1, v2, true);
    }

    // peeled tail (partial chunk, guarded scalar loads)
    {
        const int tb = B0 + (T << 6);
        if (tb < B8) {                 // wave-uniform
            const int i = tb + lane;
            float sc = 0.f, v0 = 0.f, v1 = 0.f, v2 = 0.f;
            if (i < B8) {
                sc = (float)z[i];
                v0 = pos[3 * i]; v1 = pos[3 * i + 1]; v2 = pos[3 * i + 2];
            }
            body(i, sc, v0, v1, v2, i < B8);
        }
    }

    // butterfly reductions (converged)
#pragma unroll
    for (int off = 32; off >= 1; off >>= 1) {
        tot += __shfl_xor(tot, off);
        s1  += __shfl_xor(s1,  off);
        s2  += __shfl_xor(s2,  off);
        s3  += __shfl_xor(s3,  off);
        s4  += __shfl_xor(s4,  off);
        s5  += __shfl_xor(s5,  off);
        s6  += __shfl_xor(s6,  off);
        s7  += __shfl_xor(s7,  off);
    }

    // per-graph sums from prefixes
    const float a0 = tot - s1, a1 = s1 - s2, a2 = s2 - s3, a3 = s3 - s4;
    const float a4 = s4 - s5,  a5 = s5 - s6, a6 = s6 - s7, a7 = s7;

    const int gw0 = bg0 + wid * W_GRAPHS;
    if (lane < W_GRAPHS && gw0 + lane < n_graphs) {
        float sel = (lane == 0) ? a0
                  : (lane == 1) ? a1
                  : (lane == 2) ? a2
                  : (lane == 3) ? a3
                  : (lane == 4) ? a4
                  : (lane == 5) ? a5
                  : (lane == 6) ? a6
                  :               a7;
        const float c = (float)(nbv - myb);
        out[gw0 + lane] = sel / fmaxf(c, 1.0f);
    }
}

extern "C" void kernel_launch(void* const* d_in, const int* in_sizes, int n_in,
                              void* d_out, int out_size, void* d_ws, size_t ws_size,
                              hipStream_t stream) {
    const int*   z     = (const int*)d_in[0];
    const float* pos   = (const float*)d_in[1];
    const int*   batch = (const int*)d_in[2];
    const float* w_tp  = (const float*)d_in[3];
    const float* fc_w  = (const float*)d_in[4];
    const float* fc_b  = (const float*)d_in[5];

    float* out = (float*)d_out;
    const int n        = in_sizes[0];
    const int n_graphs = out_size;

    const int blocks = (n_graphs + B_GRAPHS - 1) / B_GRAPHS;
    e3nn_fused<<<blocks, 256, 0, stream>>>(z, pos, batch, w_tp, fc_w, fc_b,
                                           out, n, n_graphs);
}

// Round 16
// 27.197 us; speedup vs baseline: 1.0251x; 1.0251x over previous
//
#include <hip/hip_runtime.h>

static constexpr float INV_SQRT2 = 0.70710678118654752f;
static constexpr float INV_SQRT3 = 0.57735026918962576f;
static constexpr float SQRT2     = 1.41421356237309505f;
static constexpr float INV_SQRT6 = 0.40824829046386302f;

static constexpr int W_GRAPHS = 8;   // graphs per wave
static constexpr int B_GRAPHS = 32;  // graphs per block (4 waves)

// branchless fast tanh: 1 - 2/(exp(2x)+1); exact at +/-inf, err ~1e-7
__device__ __forceinline__ float fast_tanh(float x) {
    const float e = __builtin_amdgcn_exp2f(x * 2.8853900817779268f); // 2*log2(e)
    const float r = __builtin_amdgcn_rcpf(e + 1.0f);
    return fmaf(-2.0f, r, 1.0f);
}

__device__ __forceinline__ float gate_p(float k, float fw) { return k > 0.f ? k * fw : 0.f; }
__device__ __forceinline__ float gate_n(float k, float fw) { return k < 0.f ? k * fw : 0.f; }

// Block owns 32 graphs; wave 0 finds the 33 boundaries once (r13 coop
// search). Each wave walks its 8 graphs' union range: T full 64-node chunks
// UNGUARDED with depth-1 register prefetch (next chunk's 4 loads issued
// before current body; full chunks are always in-bounds -> no masks, no
// clamps -- the overhead that sank r9-r12/r15), then one guarded tail chunk.
// Prefix-accumulator routing (r15-validated): a_k = s_k - s_{k+1}.
__global__ __launch_bounds__(256) void e3nn_fused(
    const int*   __restrict__ z,
    const float* __restrict__ pos,
    const int*   __restrict__ batch,
    const float* __restrict__ w_tp,
    const float* __restrict__ fc_w,
    const float* __restrict__ fc_b,
    float*       __restrict__ out,
    int n, int n_graphs)
{
    const int tid  = threadIdx.x;
    const int wid  = tid >> 6;
    const int lane = tid & 63;
    const int bg0  = blockIdx.x * B_GRAPHS;
    if (bg0 >= n_graphs) return;

    __shared__ int sbnd[B_GRAPHS + 1];

    // ---- wave 0: cooperative boundary search (one 22-probe chain/block) ----
    if (wid == 0) {
        const int tl     = (lane < B_GRAPHS) ? lane : B_GRAPHS;
        const int target = bg0 + tl;
        unsigned p2 = 1;
        while (p2 < (unsigned)n) p2 <<= 1;
        int bv = 0;
        for (unsigned step = p2 >> 1; step > 0; step >>= 1) {
            const unsigned cand = (unsigned)bv + step;
            if (cand <= (unsigned)n && batch[cand - 1] < target) bv = (int)cand;
        }
        if (lane <= B_GRAPHS) sbnd[lane] = bv;
    }
    __syncthreads();

    // ---- uniform weight prep ----
    const float kA0 = w_tp[0] * INV_SQRT2;
    const float kA1 = w_tp[1] * INV_SQRT2;
    const float kB0 = w_tp[2] * (INV_SQRT3 * INV_SQRT2);
    const float kB1 = w_tp[3] * (INV_SQRT3 * INV_SQRT2);
    const float c0  = (w_tp[4] + w_tp[6]) * INV_SQRT2;
    const float c1  = (w_tp[5] + w_tp[7]) * INV_SQRT2;
    const float wE  = w_tp[8];
    const float fw0 = fc_w[0], fw1 = fc_w[1];
    const float fb  = fc_b[0];

    const float P0 = gate_p(c0, fc_w[2]) + gate_p(c1, fc_w[5]);
    const float N0 = gate_n(c0, fc_w[2]) + gate_n(c1, fc_w[5]);
    const float P1 = gate_p(c0, fc_w[3]) + gate_p(c1, fc_w[6]);
    const float N1 = gate_n(c0, fc_w[3]) + gate_n(c1, fc_w[6]);
    const float P2 = gate_p(c0, fc_w[4]) + gate_p(c1, fc_w[7]);
    const float N2 = gate_n(c0, fc_w[4]) + gate_n(c1, fc_w[7]);
    const float k8  = wE * SQRT2,     k11 = wE * INV_SQRT2, k12 = wE * INV_SQRT6;
    const float P8  = gate_p(k8,  fc_w[8]),  N8  = gate_n(k8,  fc_w[8]);
    const float P9  = gate_p(k8,  fc_w[9]),  N9  = gate_n(k8,  fc_w[9]);
    const float P10 = gate_p(k8,  fc_w[10]), N10 = gate_n(k8,  fc_w[10]);
    const float P11 = gate_p(k11, fc_w[11]), N11 = gate_n(k11, fc_w[11]);
    const float P12 = gate_p(k12, fc_w[12]), N12 = gate_n(k12, fc_w[12]);

    // ---- this wave's boundaries ----
    const int wb = wid * W_GRAPHS;
    const int B0 = sbnd[wb + 0], B1 = sbnd[wb + 1];
    const int B2 = sbnd[wb + 2], B3 = sbnd[wb + 3];
    const int B4 = sbnd[wb + 4], B5 = sbnd[wb + 5];
    const int B6 = sbnd[wb + 6], B7 = sbnd[wb + 7];
    const int B8 = sbnd[wb + 8];
    const int myb = sbnd[wb + ((lane < W_GRAPHS) ? lane : W_GRAPHS)];
    const int nbv = sbnd[wb + ((lane < W_GRAPHS) ? lane + 1 : W_GRAPHS)];

    float tot = 0.f, s1 = 0.f, s2 = 0.f, s3 = 0.f;
    float s4  = 0.f, s5 = 0.f, s6 = 0.f, s7 = 0.f;

    auto body = [&](int i, float sc, float v0, float v1, float v2, bool valid) {
        const float v00 = v0 * v0, v11 = v1 * v1, v22 = v2 * v2;
        const float ss  = sc * sc;
        const float dr  = v00 + v11 + v22;

        float acc = fb;
        const float x0 = fmaf(ss, kA0, dr * kB0);
        const float x1 = fmaf(ss, kA1, dr * kB1);
        acc = fmaf(fmaxf(x0, 0.f), fw0, acc);
        acc = fmaf(fmaxf(x1, 0.f), fw1, acc);

        const float sv0 = sc * v0, sv1 = sc * v1, sv2 = sc * v2;
        acc = fmaf(sv0, (sv0 > 0.f ? P0 : N0), acc);
        acc = fmaf(sv1, (sv1 > 0.f ? P1 : N1), acc);
        acc = fmaf(sv2, (sv2 > 0.f ? P2 : N2), acc);

        const float t8 = v0 * v1, t9 = v1 * v2, t10 = v0 * v2;
        acc = fmaf(t8,  (t8  > 0.f ? P8  : N8 ), acc);
        acc = fmaf(t9,  (t9  > 0.f ? P9  : N9 ), acc);
        acc = fmaf(t10, (t10 > 0.f ? P10 : N10), acc);

        const float t11 = v00 - v11;
        acc = fmaf(t11, (t11 > 0.f ? P11 : N11), acc);
        const float t12 = (v22 - v00) + (v22 - v11);
        acc = fmaf(t12, (t12 > 0.f ? P12 : N12), acc);

        float y = fast_tanh(acc);
        if (!valid) y = 0.f;   // folds away in full (unguarded) chunks

        tot += y;
        s1 += (i >= B1) ? y : 0.f;
        s2 += (i >= B2) ? y : 0.f;
        s3 += (i >= B3) ? y : 0.f;
        s4 += (i >= B4) ? y : 0.f;
        s5 += (i >= B5) ? y : 0.f;
        s6 += (i >= B6) ? y : 0.f;
        s7 += (i >= B7) ? y : 0.f;
    };

    const int T = (B8 - B0) >> 6;   // full 64-node chunks

    // prologue: load chunk 0 (unguarded; full chunk is in-bounds)
    float sc = 0.f, v0 = 0.f, v1 = 0.f, v2 = 0.f;
    if (T > 0) {
        const int gi = B0 + lane;
        sc = (float)z[gi];
        v0 = pos[3 * gi]; v1 = pos[3 * gi + 1]; v2 = pos[3 * gi + 2];
    }

#pragma unroll 1
    for (int t = 0; t < T; ++t) {
        // depth-1 prefetch of chunk t+1 (wave-uniform, unguarded loads)
        float nsc = 0.f, n0 = 0.f, n1 = 0.f, n2 = 0.f;
        if (t + 1 < T) {
            const int gj = B0 + ((t + 1) << 6) + lane;
            nsc = (float)z[gj];
            n0 = pos[3 * gj]; n1 = pos[3 * gj + 1]; n2 = pos[3 * gj + 2];
        }
        body(B0 + (t << 6) + lane, sc, v0, v1, v2, true);
        sc = nsc; v0 = n0; v1 = n1; v2 = n2;
    }

    // peeled tail (partial chunk, guarded)
    {
        const int tb = B0 + (T << 6);
        if (tb < B8) {                 // wave-uniform
            const int i = tb + lane;
            float tsc = 0.f, t0 = 0.f, t1 = 0.f, t2 = 0.f;
            if (i < B8) {
                tsc = (float)z[i];
                t0 = pos[3 * i]; t1 = pos[3 * i + 1]; t2 = pos[3 * i + 2];
            }
            body(i, tsc, t0, t1, t2, i < B8);
        }
    }

    // butterfly reductions (converged)
#pragma unroll
    for (int off = 32; off >= 1; off >>= 1) {
        tot += __shfl_xor(tot, off);
        s1  += __shfl_xor(s1,  off);
        s2  += __shfl_xor(s2,  off);
        s3  += __shfl_xor(s3,  off);
        s4  += __shfl_xor(s4,  off);
        s5  += __shfl_xor(s5,  off);
        s6  += __shfl_xor(s6,  off);
        s7  += __shfl_xor(s7,  off);
    }

    // per-graph sums from prefixes
    const float a0 = tot - s1, a1 = s1 - s2, a2 = s2 - s3, a3 = s3 - s4;
    const float a4 = s4 - s5,  a5 = s5 - s6, a6 = s6 - s7, a7 = s7;

    const int gw0 = bg0 + wid * W_GRAPHS;
    if (lane < W_GRAPHS && gw0 + lane < n_graphs) {
        float sel = (lane == 0) ? a0
                  : (lane == 1) ? a1
                  : (lane == 2) ? a2
                  : (lane == 3) ? a3
                  : (lane == 4) ? a4
                  : (lane == 5) ? a5
                  : (lane == 6) ? a6
                  :               a7;
        const float c = (float)(nbv - myb);
        out[gw0 + lane] = sel / fmaxf(c, 1.0f);
    }
}

extern "C" void kernel_launch(void* const* d_in, const int* in_sizes, int n_in,
                              void* d_out, int out_size, void* d_ws, size_t ws_size,
                              hipStream_t stream) {
    const int*   z     = (const int*)d_in[0];
    const float* pos   = (const float*)d_in[1];
    const int*   batch = (const int*)d_in[2];
    const float* w_tp  = (const float*)d_in[3];
    const float* fc_w  = (const float*)d_in[4];
    const float* fc_b  = (const float*)d_in[5];

    float* out = (float*)d_out;
    const int n        = in_sizes[0];
    const int n_graphs = out_size;

    const int blocks = (n_graphs + B_GRAPHS - 1) / B_GRAPHS;
    e3nn_fused<<<blocks, 256, 0, stream>>>(z, pos, batch, w_tp, fc_w, fc_b,
                                           out, n, n_graphs);
}